// Round 1
// baseline (116.982 us; speedup 1.0000x reference)
//
#include <hip/hip_runtime.h>

// YOLO loss on MI355X.
// pred/target: (B, 14, 14, 30) f32, flattened; one thread per grid cell.
// Kernel 1: per-cell loss -> block partial sums in d_ws (float).
// Kernel 2: single block reduces partials in double, writes total/B to d_out.

__global__ __launch_bounds__(256) void yolo_cell_kernel(
    const float* __restrict__ pred, const float* __restrict__ targ,
    float* __restrict__ block_sums, int n_cells)
{
    int cell = blockIdx.x * 256 + threadIdx.x;
    float loss = 0.0f;
    if (cell < n_cells) {
        // cell stride = 30 floats = 120 B -> always 8B-aligned: use float2 loads.
        const float2* p2 = reinterpret_cast<const float2*>(pred + (size_t)cell * 30);
        const float2* t2 = reinterpret_cast<const float2*>(targ + (size_t)cell * 30);
        float pv[30], tv[30];
#pragma unroll
        for (int i = 0; i < 15; ++i) {
            float2 a = p2[i];
            float2 b = t2[i];
            pv[2*i] = a.x; pv[2*i+1] = a.y;
            tv[2*i] = b.x; tv[2*i+1] = b.y;
        }

        float conf_t = tv[4];
        if (conf_t == 0.0f) {
            // no-object cell: 0.5 * (d4^2 + d9^2); tv[4] == 0 here.
            float d4 = pv[4] - tv[4];
            float d9 = pv[9] - tv[9];
            loss = 0.5f * (d4 * d4 + d9 * d9);
        } else {
            // class loss over channels 10..29
            float cls = 0.0f;
#pragma unroll
            for (int c = 10; c < 30; ++c) {
                float d = pv[c] - tv[c];
                cls += d * d;
            }

            // target box 0 -> xyxy (mirror reference arithmetic exactly)
            float t0x = tv[0] / 14.0f, t0y = tv[1] / 14.0f;
            float tx1 = t0x - 0.5f * tv[2], ty1 = t0y - 0.5f * tv[3];
            float tx2 = t0x + 0.5f * tv[2], ty2 = t0y + 0.5f * tv[3];
            float area_t = (tx2 - tx1) * (ty2 - ty1);

            float iou0, iou1;
#pragma unroll
            for (int b = 0; b < 2; ++b) {
                float bx = pv[5*b + 0] / 14.0f, by = pv[5*b + 1] / 14.0f;
                float px1 = bx - 0.5f * pv[5*b + 2], py1 = by - 0.5f * pv[5*b + 3];
                float px2 = bx + 0.5f * pv[5*b + 2], py2 = by + 0.5f * pv[5*b + 3];
                float ltx = fmaxf(px1, tx1), lty = fmaxf(py1, ty1);
                float rbx = fminf(px2, tx2), rby = fminf(py2, ty2);
                float iw = fmaxf(rbx - ltx, 0.0f), ih = fmaxf(rby - lty, 0.0f);
                float inter = iw * ih;
                float area_p = (px2 - px1) * (py2 - py1);
                float v = inter / (area_p + area_t - inter);
                if (b == 0) iou0 = v; else iou1 = v;
            }

            // argmax over 2 boxes; tie -> box 0 (jnp.argmax first-max semantics)
            bool sel1 = iou1 > iou0;
            float max_iou = sel1 ? iou1 : iou0;

            // branchless select of responsible box (avoids scratch spill)
            float ps0 = sel1 ? pv[5] : pv[0];
            float ps1 = sel1 ? pv[6] : pv[1];
            float ps2 = sel1 ? pv[7] : pv[2];
            float ps3 = sel1 ? pv[8] : pv[3];
            float ps4 = sel1 ? pv[9] : pv[4];
            float ts0 = sel1 ? tv[5] : tv[0];
            float ts1 = sel1 ? tv[6] : tv[1];
            float ts2 = sel1 ? tv[7] : tv[2];
            float ts3 = sel1 ? tv[8] : tv[3];
            float notresp_conf = sel1 ? pv[4] : pv[9];

            float dconf = ps4 - max_iou;
            float dx = ps0 - ts0, dy = ps1 - ts1;
            float dw = sqrtf(ps2) - sqrtf(ts2);
            float dh = sqrtf(ps3) - sqrtf(ts3);
            float loc = dx * dx + dy * dy + dw * dw + dh * dh;

            loss = 5.0f * loc + 2.0f * dconf * dconf
                 + notresp_conf * notresp_conf + cls;
        }
    }

    // wave (64-lane) shuffle reduction
#pragma unroll
    for (int off = 32; off > 0; off >>= 1)
        loss += __shfl_down(loss, off, 64);

    __shared__ float wsum[4];
    int lane = threadIdx.x & 63;
    int wid  = threadIdx.x >> 6;
    if (lane == 0) wsum[wid] = loss;
    __syncthreads();
    if (threadIdx.x == 0)
        block_sums[blockIdx.x] = (wsum[0] + wsum[1]) + (wsum[2] + wsum[3]);
}

__global__ __launch_bounds__(256) void yolo_reduce_kernel(
    const float* __restrict__ block_sums, int n, double inv_batch,
    float* __restrict__ out)
{
    double acc = 0.0;
    for (int i = threadIdx.x; i < n; i += 256)
        acc += (double)block_sums[i];
#pragma unroll
    for (int off = 32; off > 0; off >>= 1)
        acc += __shfl_down(acc, off, 64);

    __shared__ double wsum[4];
    int lane = threadIdx.x & 63;
    int wid  = threadIdx.x >> 6;
    if (lane == 0) wsum[wid] = acc;
    __syncthreads();
    if (threadIdx.x == 0)
        out[0] = (float)(((wsum[0] + wsum[1]) + (wsum[2] + wsum[3])) * inv_batch);
}

extern "C" void kernel_launch(void* const* d_in, const int* in_sizes, int n_in,
                              void* d_out, int out_size, void* d_ws, size_t ws_size,
                              hipStream_t stream) {
    const float* pred = (const float*)d_in[0];
    const float* targ = (const float*)d_in[1];
    float* out = (float*)d_out;
    float* block_sums = (float*)d_ws;  // written fully before read; poison is fine

    int n_elems  = in_sizes[0];         // B*14*14*30
    int n_cells  = n_elems / 30;        // B*196
    int n_batch  = n_cells / (14 * 14); // B
    int n_blocks = (n_cells + 255) / 256;

    yolo_cell_kernel<<<n_blocks, 256, 0, stream>>>(pred, targ, block_sums, n_cells);
    yolo_reduce_kernel<<<1, 256, 0, stream>>>(block_sums, n_blocks,
                                              1.0 / (double)n_batch, out);
}

// Round 2
// 115.470 us; speedup vs baseline: 1.0131x; 1.0131x over previous
//
#include <hip/hip_runtime.h>

// YOLO loss on MI355X — round 2: LDS-staged coalesced loads.
// pred/target: (B, 14, 14, 30) f32. One 256-thread block stages a 256-cell
// tile (30720 B per tensor) into LDS via aligned float4 loads, then each
// thread computes one cell's loss from LDS. Two-kernel deterministic sum.

#define TILE 256

__global__ __launch_bounds__(256) void yolo_cell_kernel(
    const float* __restrict__ pred, const float* __restrict__ targ,
    float* __restrict__ block_sums, int n_cells)
{
    __shared__ float4 lds_p4[TILE * 30 / 4];   // 7680 floats = 30 KB
    __shared__ float4 lds_t4[TILE * 30 / 4];
    float* lds_p = reinterpret_cast<float*>(lds_p4);
    float* lds_t = reinterpret_cast<float*>(lds_t4);

    const int t = threadIdx.x;
    const int cell0 = blockIdx.x * TILE;
    const int tile_cells = min(TILE, n_cells - cell0);

    if (tile_cells == TILE) {
        // fast path: full tile, base is 16B-aligned (256*30*4 = 30720 B)
        const float4* gp = reinterpret_cast<const float4*>(pred + (size_t)cell0 * 30);
        const float4* gt = reinterpret_cast<const float4*>(targ + (size_t)cell0 * 30);
#pragma unroll
        for (int i = 0; i < 7; ++i) {
            lds_p4[i * 256 + t] = gp[i * 256 + t];
            lds_t4[i * 256 + t] = gt[i * 256 + t];
        }
        if (t < 128) {
            lds_p4[7 * 256 + t] = gp[7 * 256 + t];
            lds_t4[7 * 256 + t] = gt[7 * 256 + t];
        }
    } else {
        // generic tail path (not taken for B*196 % 256 == 0)
        int nf = tile_cells * 30;
        const float* gp = pred + (size_t)cell0 * 30;
        const float* gt = targ + (size_t)cell0 * 30;
        for (int i = t; i < nf; i += 256) {
            lds_p[i] = gp[i];
            lds_t[i] = gt[i];
        }
    }
    __syncthreads();

    float loss = 0.0f;
    if (t < tile_cells) {
        const float* pv = lds_p + t * 30;   // lane stride 30 -> 4-way LDS
        const float* tv = lds_t + t * 30;   // aliasing (1.58x), negligible

        float conf_t = tv[4];
        if (conf_t == 0.0f) {
            // no-object cell: 0.5 * (d4^2 + d9^2); tv[4] == 0 here.
            float d4 = pv[4] - tv[4];
            float d9 = pv[9] - tv[9];
            loss = 0.5f * (d4 * d4 + d9 * d9);
        } else {
            // class loss over channels 10..29
            float cls = 0.0f;
#pragma unroll
            for (int c = 10; c < 30; ++c) {
                float d = pv[c] - tv[c];
                cls += d * d;
            }

            // target box 0 -> xyxy (mirror reference arithmetic exactly)
            float t0x = tv[0] / 14.0f, t0y = tv[1] / 14.0f;
            float tx1 = t0x - 0.5f * tv[2], ty1 = t0y - 0.5f * tv[3];
            float tx2 = t0x + 0.5f * tv[2], ty2 = t0y + 0.5f * tv[3];
            float area_t = (tx2 - tx1) * (ty2 - ty1);

            float iou0, iou1;
#pragma unroll
            for (int b = 0; b < 2; ++b) {
                float bx = pv[5*b + 0] / 14.0f, by = pv[5*b + 1] / 14.0f;
                float px1 = bx - 0.5f * pv[5*b + 2], py1 = by - 0.5f * pv[5*b + 3];
                float px2 = bx + 0.5f * pv[5*b + 2], py2 = by + 0.5f * pv[5*b + 3];
                float ltx = fmaxf(px1, tx1), lty = fmaxf(py1, ty1);
                float rbx = fminf(px2, tx2), rby = fminf(py2, ty2);
                float iw = fmaxf(rbx - ltx, 0.0f), ih = fmaxf(rby - lty, 0.0f);
                float inter = iw * ih;
                float area_p = (px2 - px1) * (py2 - py1);
                float v = inter / (area_p + area_t - inter);
                if (b == 0) iou0 = v; else iou1 = v;
            }

            // argmax over 2 boxes; tie -> box 0 (jnp.argmax first-max semantics)
            bool sel1 = iou1 > iou0;
            float max_iou = sel1 ? iou1 : iou0;

            float ps0 = sel1 ? pv[5] : pv[0];
            float ps1 = sel1 ? pv[6] : pv[1];
            float ps2 = sel1 ? pv[7] : pv[2];
            float ps3 = sel1 ? pv[8] : pv[3];
            float ps4 = sel1 ? pv[9] : pv[4];
            float ts0 = sel1 ? tv[5] : tv[0];
            float ts1 = sel1 ? tv[6] : tv[1];
            float ts2 = sel1 ? tv[7] : tv[2];
            float ts3 = sel1 ? tv[8] : tv[3];
            float notresp_conf = sel1 ? pv[4] : pv[9];

            float dconf = ps4 - max_iou;
            float dx = ps0 - ts0, dy = ps1 - ts1;
            float dw = sqrtf(ps2) - sqrtf(ts2);
            float dh = sqrtf(ps3) - sqrtf(ts3);
            float loc = dx * dx + dy * dy + dw * dw + dh * dh;

            loss = 5.0f * loc + 2.0f * dconf * dconf
                 + notresp_conf * notresp_conf + cls;
        }
    }

    // wave (64-lane) shuffle reduction
#pragma unroll
    for (int off = 32; off > 0; off >>= 1)
        loss += __shfl_down(loss, off, 64);

    __shared__ float wsum[4];
    int lane = threadIdx.x & 63;
    int wid  = threadIdx.x >> 6;
    if (lane == 0) wsum[wid] = loss;
    __syncthreads();
    if (threadIdx.x == 0)
        block_sums[blockIdx.x] = (wsum[0] + wsum[1]) + (wsum[2] + wsum[3]);
}

__global__ __launch_bounds__(256) void yolo_reduce_kernel(
    const float* __restrict__ block_sums, int n, double inv_batch,
    float* __restrict__ out)
{
    double acc = 0.0;
    for (int i = threadIdx.x; i < n; i += 256)
        acc += (double)block_sums[i];
#pragma unroll
    for (int off = 32; off > 0; off >>= 1)
        acc += __shfl_down(acc, off, 64);

    __shared__ double wsum[4];
    int lane = threadIdx.x & 63;
    int wid  = threadIdx.x >> 6;
    if (lane == 0) wsum[wid] = acc;
    __syncthreads();
    if (threadIdx.x == 0)
        out[0] = (float)(((wsum[0] + wsum[1]) + (wsum[2] + wsum[3])) * inv_batch);
}

extern "C" void kernel_launch(void* const* d_in, const int* in_sizes, int n_in,
                              void* d_out, int out_size, void* d_ws, size_t ws_size,
                              hipStream_t stream) {
    const float* pred = (const float*)d_in[0];
    const float* targ = (const float*)d_in[1];
    float* out = (float*)d_out;
    float* block_sums = (float*)d_ws;  // fully written before read; poison ok

    int n_elems  = in_sizes[0];         // B*14*14*30
    int n_cells  = n_elems / 30;        // B*196
    int n_batch  = n_cells / (14 * 14); // B
    int n_blocks = (n_cells + TILE - 1) / TILE;

    yolo_cell_kernel<<<n_blocks, 256, 0, stream>>>(pred, targ, block_sums, n_cells);
    yolo_reduce_kernel<<<1, 256, 0, stream>>>(block_sums, n_blocks,
                                              1.0 / (double)n_batch, out);
}